// Round 8
// baseline (1532.523 us; speedup 1.0000x reference)
//
#include <hip/hip_runtime.h>

// x_restored: (8192, 3, 20, 20) f32
// x_distorted: (8192, 5) f32
// w1: (128, 5), w2: (1200, 128), b2: (1200,)
// conv_w: (15, 6, 3, 3), conv_b: (15,)
// out: (8192, 5, 3, 20, 20) f32

#define NB 8192

typedef __attribute__((ext_vector_type(8))) short short8;
typedef __attribute__((ext_vector_type(4))) float floatx4;

__device__ inline unsigned short f2bf(float f) {
    unsigned int u = __float_as_uint(f);
    unsigned int r = (u + 0x7FFFu + ((u >> 16) & 1u)) >> 16;
    return (unsigned short)r;
}

// ---------------- Kernel A: h = relu(x_distorted @ w1.T) -> bf16, (B,128) ----------------
__global__ __launch_bounds__(256) void mlp1_kernel(const float* __restrict__ xdist,
                                                   const float* __restrict__ w1,
                                                   unsigned short* __restrict__ hb) {
    int gid = blockIdx.x * 256 + threadIdx.x;
    int b = gid >> 7, j = gid & 127;
    const float* xr = xdist + b * 5;
    const float* wr = w1 + j * 5;
    float s = xr[0] * wr[0];
    s = fmaf(xr[1], wr[1], s);
    s = fmaf(xr[2], wr[2], s);
    s = fmaf(xr[3], wr[3], s);
    s = fmaf(xr[4], wr[4], s);
    hb[gid] = f2bf(fmaxf(s, 0.0f));
}

// ---------------- cast w2 -> bf16 ----------------
__global__ __launch_bounds__(256) void castw2_kernel(const float* __restrict__ w2,
                                                     unsigned short* __restrict__ w2b) {
    int i = blockIdx.x * 256 + threadIdx.x;   // 1200*128 = 153600 exactly
    w2b[i] = f2bf(w2[i]);
}

// ---------------- Kernel B: xd = h @ w2.T + b2 via bf16 MFMA ----------------
__global__ __launch_bounds__(256) void mlp2_mfma(const unsigned short* __restrict__ hb,
                                                 const unsigned short* __restrict__ w2b,
                                                 const float* __restrict__ b2,
                                                 float* __restrict__ xd) {
    const int tid = threadIdx.x;
    const int lane = tid & 63, wv = tid >> 6;
    const int tile = blockIdx.x * 4 + wv;          // 0..3199
    const int mt = tile / 25, nt = tile - mt * 25;
    const int rsel = lane & 15, kg = lane >> 4;

    short8 a[4][4], bfr[3][4];
    #pragma unroll
    for (int mi = 0; mi < 4; ++mi) {
        const unsigned short* ap = hb + (size_t)(mt * 64 + mi * 16 + rsel) * 128 + kg * 8;
        #pragma unroll
        for (int ks = 0; ks < 4; ++ks) a[mi][ks] = *(const short8*)(ap + ks * 32);
    }
    #pragma unroll
    for (int ni = 0; ni < 3; ++ni) {
        const unsigned short* bp = w2b + (size_t)(nt * 48 + ni * 16 + rsel) * 128 + kg * 8;
        #pragma unroll
        for (int ks = 0; ks < 4; ++ks) bfr[ni][ks] = *(const short8*)(bp + ks * 32);
    }
    floatx4 acc[4][3];
    #pragma unroll
    for (int mi = 0; mi < 4; ++mi)
        #pragma unroll
        for (int ni = 0; ni < 3; ++ni)
            acc[mi][ni] = (floatx4){0.f, 0.f, 0.f, 0.f};

    #pragma unroll
    for (int ks = 0; ks < 4; ++ks)
        #pragma unroll
        for (int mi = 0; mi < 4; ++mi)
            #pragma unroll
            for (int ni = 0; ni < 3; ++ni)
                acc[mi][ni] = __builtin_amdgcn_mfma_f32_16x16x32_bf16(
                    a[mi][ks], bfr[ni][ks], acc[mi][ni], 0, 0, 0);

    #pragma unroll
    for (int ni = 0; ni < 3; ++ni) {
        float bias = b2[nt * 48 + ni * 16 + rsel];
        #pragma unroll
        for (int mi = 0; mi < 4; ++mi) {
            #pragma unroll
            for (int r = 0; r < 4; ++r) {
                int m = mt * 64 + mi * 16 + kg * 4 + r;
                xd[(size_t)m * 1200 + nt * 48 + ni * 16 + rsel] = acc[mi][ni][r] + bias;
            }
        }
    }
}

#define GIDX(i, j) ((i) * 5 - (i) * ((i) - 1) / 2 + ((j) - (i)))
#define GF(i, j) Gm[((i) <= (j)) ? GIDX(i, j) : GIDX(j, i)]

#define PXS 23           // padded row stride (odd -> 23*r spreads all banks)
#define PXP 506          // plane stride = 22*23
#define WLS 401          // wl row stride (odd)

// ---------------- Kernel C: conv(6->15) + Gram-space GS, 256 thr / sample ----------------
// LDS union: xpad (3036 f) and wl[15][401] (6015 f) share smem; conv holds its 24 outputs
// in registers across the barrier, then overwrites. Total LDS 27.5 KB -> 5 blocks/CU.
// Conv: thread t<250 owns channel-triple g=t/50, output rows r=s/5 and r+10, col quad
// 4*(s%5). Odd strides + consecutive-address scalar Gram/combine reads -> ~conflict-free.
__global__ __launch_bounds__(256, 5) void conv_gs_kernel(const float* __restrict__ xd,
                                                         const float* __restrict__ xres,
                                                         const float* __restrict__ cw,
                                                         const float* __restrict__ cb,
                                                         float* __restrict__ out) {
    const int b = blockIdx.x;
    const int tid = threadIdx.x;  // 0..255
    const int lane = tid & 63, wv = tid >> 6;
    __shared__ __align__(16) float smem[6015];   // xpad[0..3035] then reused as wl[15*401]
    __shared__ float cwl[810];                   // weights as [ci*9+ky*3+tap][o]
    __shared__ float gred[4][16];

    // stage transposed weights
    for (int i = tid; i < 810; i += 256) cwl[i] = cw[(i % 15) * 54 + i / 15];

    // zero only the pad border: per plane 86 cells (rows 0,21; cols 0,21)
    for (int i = tid; i < 516; i += 256) {
        int pl = i / 86, j = i % 86;
        int y, x;
        if (j < 23)      { y = 0;       x = j; }
        else if (j < 46) { y = 21;      x = j - 23; }
        else if (j < 66) { y = j - 45;  x = 0; }       // rows 1..20, col 0
        else             { y = j - 65;  x = 21; }      // rows 1..20, col 21
        smem[pl * PXP + y * PXS + x] = 0.f;
    }

    // interior fill: 600 float4 (ch 0-2 = xd, 3-5 = xres), scalar LDS writes (disjoint
    // from border -> no barrier needed between zero and fill)
    const float* src0 = xd + (size_t)b * 1200;
    const float* src1 = xres + (size_t)b * 1200;
    for (int j = tid; j < 600; j += 256) {
        float4 v = (j < 300) ? ((const float4*)src0)[j] : ((const float4*)src1)[j - 300];
        int c = j / 100, rr = (j % 100) * 4, y = rr / 20, x = rr % 20;
        float* dst = smem + c * PXP + (y + 1) * PXS + (x + 1);
        dst[0] = v.x; dst[1] = v.y; dst[2] = v.z; dst[3] = v.w;
    }
    __syncthreads();

    // ---- conv phase (reads smem-as-xpad, accumulates in regs) ----
    const bool act = (tid < 250);
    const int tt = act ? tid : 249;
    const int g = tt / 50, s = tt % 50;
    const int r = s / 5, xc4 = 4 * (s % 5);

    float a2[2][3][4];   // [half(row r / r+10)][cc][slot]
    #pragma unroll
    for (int cc = 0; cc < 3; ++cc) {
        float bo = cb[3 * g + cc];
        #pragma unroll
        for (int h = 0; h < 2; ++h)
            #pragma unroll
            for (int sl = 0; sl < 4; ++sl) a2[h][cc][sl] = bo;
    }

    #pragma unroll
    for (int ci = 0; ci < 6; ++ci) {
        #pragma unroll
        for (int h = 0; h < 2; ++h) {
            const int rb = r + h * 10;
            float P[3][6];
            #pragma unroll
            for (int kk = 0; kk < 3; ++kk) {
                const float* rp = smem + ci * PXP + (rb + kk) * PXS + xc4;
                #pragma unroll
                for (int t = 0; t < 6; ++t) P[kk][t] = rp[t];
            }
            #pragma unroll
            for (int ky = 0; ky < 3; ++ky) {
                const int tb = (ci * 9 + ky * 3) * 15 + 3 * g;
                #pragma unroll
                for (int cc = 0; cc < 3; ++cc) {
                    float w0 = cwl[tb + cc], w1v = cwl[tb + 15 + cc], w2v = cwl[tb + 30 + cc];
                    #pragma unroll
                    for (int sl = 0; sl < 4; ++sl)
                        a2[h][cc][sl] = fmaf(P[ky][sl], w0,
                                        fmaf(P[ky][sl + 1], w1v,
                                        fmaf(P[ky][sl + 2], w2v, a2[h][cc][sl])));
                }
            }
        }
    }
    __syncthreads();   // all xpad reads done; smem becomes wl

    if (act) {
        #pragma unroll
        for (int h = 0; h < 2; ++h) {
            const int pb = (r + h * 10) * 20 + xc4;
            #pragma unroll
            for (int cc = 0; cc < 3; ++cc) {
                #pragma unroll
                for (int sl = 0; sl < 4; ++sl)
                    smem[(3 * g + cc) * WLS + pb + sl] = a2[h][cc][sl];
            }
        }
    }
    __syncthreads();

    // ---- Gram phase: pos = tid (+256 if tid<144); consecutive-address scalar reads ----
    float g15[15];
    #pragma unroll
    for (int v = 0; v < 15; ++v) g15[v] = 0.f;
    #pragma unroll
    for (int pp = 0; pp < 2; ++pp) {
        if (pp == 0 || tid < 144) {
            const int pos = tid + pp * 256;
            #pragma unroll
            for (int cc = 0; cc < 3; ++cc) {
                float ch[5];
                #pragma unroll
                for (int i = 0; i < 5; ++i) ch[i] = smem[(3 * i + cc) * WLS + pos];
                int p = 0;
                #pragma unroll
                for (int i = 0; i < 5; ++i)
                    #pragma unroll
                    for (int j = i; j < 5; ++j, ++p)
                        g15[p] = fmaf(ch[i], ch[j], g15[p]);
            }
        }
    }
    #pragma unroll
    for (int m = 32; m; m >>= 1) {
        #pragma unroll
        for (int v = 0; v < 15; ++v) g15[v] += __shfl_xor(g15[v], m, 64);
    }
    if (lane == 0) {
        #pragma unroll
        for (int v = 0; v < 15; ++v) gred[wv][v] = g15[v];
    }
    __syncthreads();

    // ---- A-matrix (Gram-space modified GS, per-thread redundant) + combine + store ----
    float Gm[15];
    #pragma unroll
    for (int v = 0; v < 15; ++v)
        Gm[v] = gred[0][v] + gred[1][v] + gred[2][v] + gred[3][v];

    float A[5][5];
    #pragma unroll
    for (int i = 0; i < 5; ++i)
        #pragma unroll
        for (int j = 0; j < 5; ++j) A[i][j] = (i == j) ? 1.f : 0.f;
    #pragma unroll
    for (int j = 0; j < 4; ++j) {
        float v[5];
        #pragma unroll
        for (int rr = 0; rr < 5; ++rr) {
            float s0 = 0.f;
            #pragma unroll
            for (int k = 0; k < 5; ++k)
                if (k <= j) s0 = fmaf(A[j][k], GF(k, rr), s0);
            v[rr] = s0;
        }
        float dj = 0.f;
        #pragma unroll
        for (int k = 0; k < 5; ++k)
            if (k <= j) dj = fmaf(A[j][k], v[k], dj);
        float rd = 1.0f / dj;
        #pragma unroll
        for (int i = j + 1; i < 5; ++i) {
            float cij = 0.f;
            #pragma unroll
            for (int k = 0; k < 5; ++k)
                if (k <= i) cij = fmaf(A[i][k], v[k], cij);
            cij *= rd;
            #pragma unroll
            for (int k = 0; k < 5; ++k)
                if (k <= j) A[i][k] = fmaf(-cij, A[j][k], A[i][k]);
        }
    }

    float* ob = out + (size_t)b * 6000;
    #pragma unroll
    for (int pp = 0; pp < 2; ++pp) {
        if (pp == 0 || tid < 144) {
            const int pos = tid + pp * 256;
            #pragma unroll
            for (int cc = 0; cc < 3; ++cc) {
                float wq[5];
                #pragma unroll
                for (int k = 0; k < 5; ++k) wq[k] = smem[(3 * k + cc) * WLS + pos];
                #pragma unroll
                for (int d = 4; d >= 0; --d) {
                    float u = wq[d];
                    #pragma unroll
                    for (int k = 0; k < d; ++k) u = fmaf(A[d][k], wq[k], u);
                    ob[(3 * d + cc) * 400 + pos] = u;
                }
            }
        }
    }
}

extern "C" void kernel_launch(void* const* d_in, const int* in_sizes, int n_in,
                              void* d_out, int out_size, void* d_ws, size_t ws_size,
                              hipStream_t stream) {
    const float* x_restored  = (const float*)d_in[0];
    const float* x_distorted = (const float*)d_in[1];
    const float* w1          = (const float*)d_in[2];
    const float* w2          = (const float*)d_in[3];
    const float* b2          = (const float*)d_in[4];
    const float* conv_w      = (const float*)d_in[5];
    const float* conv_b      = (const float*)d_in[6];
    float* out = (float*)d_out;

    float* xd = (float*)d_ws;                                         // 39.3 MB
    unsigned short* hb  = (unsigned short*)(xd + (size_t)NB * 1200);  // 2 MB
    unsigned short* w2b = hb + (size_t)NB * 128;                      // 0.3 MB

    mlp1_kernel<<<(NB * 128) / 256, 256, 0, stream>>>(x_distorted, w1, hb);
    castw2_kernel<<<(1200 * 128) / 256, 256, 0, stream>>>(w2, w2b);
    mlp2_mfma<<<(128 * 25) / 4, 256, 0, stream>>>(hb, w2b, b2, xd);
    conv_gs_kernel<<<NB, 256, 0, stream>>>(xd, x_restored, conv_w, conv_b, out);
}

// Round 9
// 861.269 us; speedup vs baseline: 1.7794x; 1.7794x over previous
//
#include <hip/hip_runtime.h>

// x_restored: (8192, 3, 20, 20) f32
// x_distorted: (8192, 5) f32
// w1: (128, 5), w2: (1200, 128), b2: (1200,)
// conv_w: (15, 6, 3, 3), conv_b: (15,)
// out: (8192, 5, 3, 20, 20) f32

#define NB 8192

typedef __attribute__((ext_vector_type(8))) short short8;
typedef __attribute__((ext_vector_type(4))) float floatx4;

__device__ inline unsigned short f2bf(float f) {
    unsigned int u = __float_as_uint(f);
    unsigned int r = (u + 0x7FFFu + ((u >> 16) & 1u)) >> 16;
    return (unsigned short)r;
}

// ---------------- Kernel A: h = relu(x_distorted @ w1.T) -> bf16, (B,128) ----------------
__global__ __launch_bounds__(256) void mlp1_kernel(const float* __restrict__ xdist,
                                                   const float* __restrict__ w1,
                                                   unsigned short* __restrict__ hb) {
    int gid = blockIdx.x * 256 + threadIdx.x;
    int b = gid >> 7, j = gid & 127;
    const float* xr = xdist + b * 5;
    const float* wr = w1 + j * 5;
    float s = xr[0] * wr[0];
    s = fmaf(xr[1], wr[1], s);
    s = fmaf(xr[2], wr[2], s);
    s = fmaf(xr[3], wr[3], s);
    s = fmaf(xr[4], wr[4], s);
    hb[gid] = f2bf(fmaxf(s, 0.0f));
}

// ---------------- cast w2 -> bf16 ----------------
__global__ __launch_bounds__(256) void castw2_kernel(const float* __restrict__ w2,
                                                     unsigned short* __restrict__ w2b) {
    int i = blockIdx.x * 256 + threadIdx.x;   // 1200*128 = 153600 exactly
    w2b[i] = f2bf(w2[i]);
}

// ---------------- Kernel B: xd = h @ w2.T + b2 via bf16 MFMA ----------------
__global__ __launch_bounds__(256) void mlp2_mfma(const unsigned short* __restrict__ hb,
                                                 const unsigned short* __restrict__ w2b,
                                                 const float* __restrict__ b2,
                                                 float* __restrict__ xd) {
    const int tid = threadIdx.x;
    const int lane = tid & 63, wv = tid >> 6;
    const int tile = blockIdx.x * 4 + wv;          // 0..3199
    const int mt = tile / 25, nt = tile - mt * 25;
    const int rsel = lane & 15, kg = lane >> 4;

    short8 a[4][4], bfr[3][4];
    #pragma unroll
    for (int mi = 0; mi < 4; ++mi) {
        const unsigned short* ap = hb + (size_t)(mt * 64 + mi * 16 + rsel) * 128 + kg * 8;
        #pragma unroll
        for (int ks = 0; ks < 4; ++ks) a[mi][ks] = *(const short8*)(ap + ks * 32);
    }
    #pragma unroll
    for (int ni = 0; ni < 3; ++ni) {
        const unsigned short* bp = w2b + (size_t)(nt * 48 + ni * 16 + rsel) * 128 + kg * 8;
        #pragma unroll
        for (int ks = 0; ks < 4; ++ks) bfr[ni][ks] = *(const short8*)(bp + ks * 32);
    }
    floatx4 acc[4][3];
    #pragma unroll
    for (int mi = 0; mi < 4; ++mi)
        #pragma unroll
        for (int ni = 0; ni < 3; ++ni)
            acc[mi][ni] = (floatx4){0.f, 0.f, 0.f, 0.f};

    #pragma unroll
    for (int ks = 0; ks < 4; ++ks)
        #pragma unroll
        for (int mi = 0; mi < 4; ++mi)
            #pragma unroll
            for (int ni = 0; ni < 3; ++ni)
                acc[mi][ni] = __builtin_amdgcn_mfma_f32_16x16x32_bf16(
                    a[mi][ks], bfr[ni][ks], acc[mi][ni], 0, 0, 0);

    #pragma unroll
    for (int ni = 0; ni < 3; ++ni) {
        float bias = b2[nt * 48 + ni * 16 + rsel];
        #pragma unroll
        for (int mi = 0; mi < 4; ++mi) {
            #pragma unroll
            for (int r = 0; r < 4; ++r) {
                int m = mt * 64 + mi * 16 + kg * 4 + r;
                xd[(size_t)m * 1200 + nt * 48 + ni * 16 + rsel] = acc[mi][ni][r] + bias;
            }
        }
    }
}

#define GIDX(i, j) ((i) * 5 - (i) * ((i) - 1) / 2 + ((j) - (i)))
#define GF(i, j) Gm[((i) <= (j)) ? GIDX(i, j) : GIDX(j, i)]

// ---------------- Kernel C: conv(6->15) + Gram-space GS, 256 thr / sample ----------------
// R6 structure (best known: no spills at launch_bounds(256,4)) + two fixes:
//  (a) Gram/combine use SCALAR consecutive-address LDS reads (pos=tid, tid+200) --
//      R6's float4@4*tid reads were 8-way bank conflicts (4t mod 32 period 8).
//  (b) smem union: xpad (2908 f, stride 22) overlays wl[15][404] (6060 f). Conv keeps its
//      24 outputs in registers across one barrier. LDS 39.4 -> 27.7 KB = 5 blocks/CU.
__global__ __launch_bounds__(256, 4) void conv_gs_kernel(const float* __restrict__ xd,
                                                         const float* __restrict__ xres,
                                                         const float* __restrict__ cw,
                                                         const float* __restrict__ cb,
                                                         float* __restrict__ out) {
    const int b = blockIdx.x;
    const int tid = threadIdx.x;  // 0..255
    const int lane = tid & 63, wv = tid >> 6;
    __shared__ __align__(16) float smem[6060];  // xpad[0..2907] -> then wl[15][404]
    __shared__ float cwl[810];                  // weights as [ci*9+ky*3+tap][o]
    __shared__ float gred[4][16];

    // zero xpad region (727 float4)
    float4* xf4 = (float4*)smem;
    #pragma unroll
    for (int i = 0; i < 3; ++i) {
        int idx = tid + i * 256;
        if (idx < 727) xf4[idx] = make_float4(0.f, 0.f, 0.f, 0.f);
    }
    // stage transposed weights: cwl[(ci*9+ky*3+tap)*15 + o] = cw[o*54 + ...]
    #pragma unroll
    for (int i = 0; i < 4; ++i) {
        int idx = tid + i * 256;
        if (idx < 810) cwl[idx] = cw[(idx % 15) * 54 + idx / 15];
    }
    __syncthreads();

    // fill xpad interior (600 float4: ch 0-2 = xd, 3-5 = xres)
    const float* src0 = xd + (size_t)b * 1200;
    const float* src1 = xres + (size_t)b * 1200;
    #pragma unroll
    for (int i = 0; i < 3; ++i) {
        int j = tid + i * 256;
        if (j < 600) {
            float4 v = (j < 300) ? ((const float4*)src0)[j] : ((const float4*)src1)[j - 300];
            int c = j / 100, rr = (j % 100) * 4, y = rr / 20, x = rr % 20;
            float* dst = smem + c * 484 + (y + 1) * 22 + (x + 1);
            dst[0] = v.x; dst[1] = v.y; dst[2] = v.z; dst[3] = v.w;
        }
    }
    __syncthreads();

    // ---- conv phase: thread t<250 owns channel-triple g=t/50, rows y0=2*(s/5),y0+1,
    //      col quad 4*(s%5). 24 outputs in registers across the union barrier. ----
    const bool act = (tid < 250);
    const int tt = act ? tid : 249;
    const int g = tt / 50, s = tt % 50;
    const int r2 = s / 5, xc = s % 5;
    const int y0 = 2 * r2, xq = 4 * xc;
    const int o0 = 3 * g;
    const int q0 = y0 * 5 + xc;               // quad index of row y0

    float a0[3][4], a1[3][4];
    #pragma unroll
    for (int cc = 0; cc < 3; ++cc) {
        float bo = cb[o0 + cc];
        #pragma unroll
        for (int sl = 0; sl < 4; ++sl) { a0[cc][sl] = bo; a1[cc][sl] = bo; }
    }

    #pragma unroll
    for (int ci = 0; ci < 6; ++ci) {
        float P[4][6];
        #pragma unroll
        for (int rr = 0; rr < 4; ++rr) {
            const float* rp = smem + ci * 484 + (y0 + rr) * 22 + xq;
            #pragma unroll
            for (int t = 0; t < 6; ++t) P[rr][t] = rp[t];
        }
        #pragma unroll
        for (int ky = 0; ky < 3; ++ky) {
            const int tb = (ci * 9 + ky * 3) * 15 + o0;
            #pragma unroll
            for (int cc = 0; cc < 3; ++cc) {
                float w0 = cwl[tb + cc], w1v = cwl[tb + 15 + cc], w2v = cwl[tb + 30 + cc];
                #pragma unroll
                for (int sl = 0; sl < 4; ++sl) {
                    a0[cc][sl] = fmaf(P[ky][sl], w0,
                                 fmaf(P[ky][sl + 1], w1v,
                                 fmaf(P[ky][sl + 2], w2v, a0[cc][sl])));
                    a1[cc][sl] = fmaf(P[ky + 1][sl], w0,
                                 fmaf(P[ky + 1][sl + 1], w1v,
                                 fmaf(P[ky + 1][sl + 2], w2v, a1[cc][sl])));
                }
            }
        }
    }
    __syncthreads();   // all xpad reads complete; smem becomes wl[15][404]

    if (act) {
        #pragma unroll
        for (int cc = 0; cc < 3; ++cc) {
            *(float4*)(smem + (o0 + cc) * 404 + 4 * q0) =
                make_float4(a0[cc][0], a0[cc][1], a0[cc][2], a0[cc][3]);
            *(float4*)(smem + (o0 + cc) * 404 + 4 * (q0 + 5)) =
                make_float4(a1[cc][0], a1[cc][1], a1[cc][2], a1[cc][3]);
        }
    }
    __syncthreads();

    // ---- Gram phase: tid<200, pos = tid, tid+200; consecutive-address scalar reads ----
    float g15[15];
    #pragma unroll
    for (int v = 0; v < 15; ++v) g15[v] = 0.f;
    if (tid < 200) {
        #pragma unroll
        for (int pp = 0; pp < 2; ++pp) {
            const int pos = tid + pp * 200;
            #pragma unroll
            for (int cc = 0; cc < 3; ++cc) {
                float ch[5];
                #pragma unroll
                for (int i = 0; i < 5; ++i) ch[i] = smem[(3 * i + cc) * 404 + pos];
                int p = 0;
                #pragma unroll
                for (int i = 0; i < 5; ++i)
                    #pragma unroll
                    for (int j = i; j < 5; ++j, ++p)
                        g15[p] = fmaf(ch[i], ch[j], g15[p]);
            }
        }
    }
    #pragma unroll
    for (int m = 32; m; m >>= 1) {
        #pragma unroll
        for (int v = 0; v < 15; ++v) g15[v] += __shfl_xor(g15[v], m, 64);
    }
    if (lane == 0) {
        #pragma unroll
        for (int v = 0; v < 15; ++v) gred[wv][v] = g15[v];
    }
    __syncthreads();

    // ---- A-matrix (Gram-space modified GS, per-thread redundant) + combine + store ----
    float Gm[15];
    #pragma unroll
    for (int v = 0; v < 15; ++v)
        Gm[v] = gred[0][v] + gred[1][v] + gred[2][v] + gred[3][v];

    float A[5][5];
    #pragma unroll
    for (int i = 0; i < 5; ++i)
        #pragma unroll
        for (int j = 0; j < 5; ++j) A[i][j] = (i == j) ? 1.f : 0.f;
    #pragma unroll
    for (int j = 0; j < 4; ++j) {
        float v[5];
        #pragma unroll
        for (int rr = 0; rr < 5; ++rr) {
            float s0 = 0.f;
            #pragma unroll
            for (int k = 0; k < 5; ++k)
                if (k <= j) s0 = fmaf(A[j][k], GF(k, rr), s0);
            v[rr] = s0;
        }
        float dj = 0.f;
        #pragma unroll
        for (int k = 0; k < 5; ++k)
            if (k <= j) dj = fmaf(A[j][k], v[k], dj);
        float rd = 1.0f / dj;
        #pragma unroll
        for (int i = j + 1; i < 5; ++i) {
            float cij = 0.f;
            #pragma unroll
            for (int k = 0; k < 5; ++k)
                if (k <= i) cij = fmaf(A[i][k], v[k], cij);
            cij *= rd;
            #pragma unroll
            for (int k = 0; k < 5; ++k)
                if (k <= j) A[i][k] = fmaf(-cij, A[j][k], A[i][k]);
        }
    }

    if (tid < 200) {
        float* ob = out + (size_t)b * 6000;
        #pragma unroll
        for (int pp = 0; pp < 2; ++pp) {
            const int pos = tid + pp * 200;
            #pragma unroll
            for (int cc = 0; cc < 3; ++cc) {
                float wq[5];
                #pragma unroll
                for (int k = 0; k < 5; ++k) wq[k] = smem[(3 * k + cc) * 404 + pos];
                #pragma unroll
                for (int d = 4; d >= 0; --d) {
                    float u = wq[d];
                    #pragma unroll
                    for (int k = 0; k < d; ++k) u = fmaf(A[d][k], wq[k], u);
                    ob[(3 * d + cc) * 400 + pos] = u;
                }
            }
        }
    }
}

extern "C" void kernel_launch(void* const* d_in, const int* in_sizes, int n_in,
                              void* d_out, int out_size, void* d_ws, size_t ws_size,
                              hipStream_t stream) {
    const float* x_restored  = (const float*)d_in[0];
    const float* x_distorted = (const float*)d_in[1];
    const float* w1          = (const float*)d_in[2];
    const float* w2          = (const float*)d_in[3];
    const float* b2          = (const float*)d_in[4];
    const float* conv_w      = (const float*)d_in[5];
    const float* conv_b      = (const float*)d_in[6];
    float* out = (float*)d_out;

    float* xd = (float*)d_ws;                                         // 39.3 MB
    unsigned short* hb  = (unsigned short*)(xd + (size_t)NB * 1200);  // 2 MB
    unsigned short* w2b = hb + (size_t)NB * 128;                      // 0.3 MB

    mlp1_kernel<<<(NB * 128) / 256, 256, 0, stream>>>(x_distorted, w1, hb);
    castw2_kernel<<<(1200 * 128) / 256, 256, 0, stream>>>(w2, w2b);
    mlp2_mfma<<<(128 * 25) / 4, 256, 0, stream>>>(hb, w2b, b2, xd);
    conv_gs_kernel<<<NB, 256, 0, stream>>>(xd, x_restored, conv_w, conv_b, out);
}

// Round 11
// 251.555 us; speedup vs baseline: 6.0922x; 3.4238x over previous
//
#include <hip/hip_runtime.h>

// x_restored: (8192, 3, 20, 20) f32
// x_distorted: (8192, 5) f32
// w1: (128, 5), w2: (1200, 128), b2: (1200,)
// conv_w: (15, 6, 3, 3), conv_b: (15,)
// out: (8192, 5, 3, 20, 20) f32

#define NB 8192

typedef __attribute__((ext_vector_type(8))) short short8;
typedef __attribute__((ext_vector_type(4))) float floatx4;

__device__ inline unsigned short f2bf(float f) {
    unsigned int u = __float_as_uint(f);
    unsigned int r = (u + 0x7FFFu + ((u >> 16) & 1u)) >> 16;
    return (unsigned short)r;
}

// ---------------- Kernel A: h = relu(x_distorted @ w1.T) -> bf16, (B,128) ----------------
__global__ __launch_bounds__(256) void mlp1_kernel(const float* __restrict__ xdist,
                                                   const float* __restrict__ w1,
                                                   unsigned short* __restrict__ hb) {
    int gid = blockIdx.x * 256 + threadIdx.x;
    int b = gid >> 7, j = gid & 127;
    const float* xr = xdist + b * 5;
    const float* wr = w1 + j * 5;
    float s = xr[0] * wr[0];
    s = fmaf(xr[1], wr[1], s);
    s = fmaf(xr[2], wr[2], s);
    s = fmaf(xr[3], wr[3], s);
    s = fmaf(xr[4], wr[4], s);
    hb[gid] = f2bf(fmaxf(s, 0.0f));
}

// ---------------- cast w2 -> bf16 ----------------
__global__ __launch_bounds__(256) void castw2_kernel(const float* __restrict__ w2,
                                                     unsigned short* __restrict__ w2b) {
    int i = blockIdx.x * 256 + threadIdx.x;   // 1200*128 = 153600 exactly
    w2b[i] = f2bf(w2[i]);
}

// ---------------- Kernel B: xd = h @ w2.T + b2 via bf16 MFMA ----------------
__global__ __launch_bounds__(256) void mlp2_mfma(const unsigned short* __restrict__ hb,
                                                 const unsigned short* __restrict__ w2b,
                                                 const float* __restrict__ b2,
                                                 float* __restrict__ xd) {
    const int tid = threadIdx.x;
    const int lane = tid & 63, wv = tid >> 6;
    const int tile = blockIdx.x * 4 + wv;          // 0..3199
    const int mt = tile / 25, nt = tile - mt * 25;
    const int rsel = lane & 15, kg = lane >> 4;

    short8 a[4][4], bfr[3][4];
    #pragma unroll
    for (int mi = 0; mi < 4; ++mi) {
        const unsigned short* ap = hb + (size_t)(mt * 64 + mi * 16 + rsel) * 128 + kg * 8;
        #pragma unroll
        for (int ks = 0; ks < 4; ++ks) a[mi][ks] = *(const short8*)(ap + ks * 32);
    }
    #pragma unroll
    for (int ni = 0; ni < 3; ++ni) {
        const unsigned short* bp = w2b + (size_t)(nt * 48 + ni * 16 + rsel) * 128 + kg * 8;
        #pragma unroll
        for (int ks = 0; ks < 4; ++ks) bfr[ni][ks] = *(const short8*)(bp + ks * 32);
    }
    floatx4 acc[4][3];
    #pragma unroll
    for (int mi = 0; mi < 4; ++mi)
        #pragma unroll
        for (int ni = 0; ni < 3; ++ni)
            acc[mi][ni] = (floatx4){0.f, 0.f, 0.f, 0.f};

    #pragma unroll
    for (int ks = 0; ks < 4; ++ks)
        #pragma unroll
        for (int mi = 0; mi < 4; ++mi)
            #pragma unroll
            for (int ni = 0; ni < 3; ++ni)
                acc[mi][ni] = __builtin_amdgcn_mfma_f32_16x16x32_bf16(
                    a[mi][ks], bfr[ni][ks], acc[mi][ni], 0, 0, 0);

    #pragma unroll
    for (int ni = 0; ni < 3; ++ni) {
        float bias = b2[nt * 48 + ni * 16 + rsel];
        #pragma unroll
        for (int mi = 0; mi < 4; ++mi) {
            #pragma unroll
            for (int r = 0; r < 4; ++r) {
                int m = mt * 64 + mi * 16 + kg * 4 + r;
                xd[(size_t)m * 1200 + nt * 48 + ni * 16 + rsel] = acc[mi][ni][r] + bias;
            }
        }
    }
}

#define GIDX(i, j) ((i) * 5 - (i) * ((i) - 1) / 2 + ((j) - (i)))
#define GF(i, j) Gm[((i) <= (j)) ? GIDX(i, j) : GIDX(j, i)]

// ---------------- Kernel C: conv(6->15) + Gram-space GS, 512 thr / sample ----------------
// Per-phase live sets kept < ~50 regs BY CONSTRUCTION (lesson of R3/R5/R8/R9: the hipcc
// allocator pins 64 VGPRs for these kernels and spills anything bigger):
//   conv: thread u<500 owns ONE row-quad (row r, cols 4xc..4xc+3) and channel triple
//   g=u/100: 12 accs + 18 window + 9 weights. Writes wl directly (separate buffer, no
//   union, nothing live across barriers). Gram/combine: consecutive-address scalar reads
//   (pos=tid<400), conflict-free. LDS 39.6 KB -> 4 blocks/CU x 8 waves = full occupancy.
__global__ __launch_bounds__(512) void conv_gs_kernel(const float* __restrict__ xd,
                                                      const float* __restrict__ xres,
                                                      const float* __restrict__ cw,
                                                      const float* __restrict__ cb,
                                                      float* __restrict__ out) {
    const int b = blockIdx.x;
    const int tid = threadIdx.x;  // 0..511
    const int lane = tid & 63, wv = tid >> 6;
    __shared__ __align__(16) float xpad[2908];   // 6 padded 22x22 planes
    __shared__ __align__(16) float wl[15 * 404]; // conv output [o][pos], stride 404
    __shared__ float cwl[810];                   // weights as [ci*9+ky*3+tap][o]
    __shared__ float gred[8][16];

    // zero xpad (727 float4) + stage transposed weights
    float4* xf4 = (float4*)xpad;
    #pragma unroll
    for (int i = 0; i < 2; ++i) {
        int idx = tid + i * 512;
        if (idx < 727) xf4[idx] = make_float4(0.f, 0.f, 0.f, 0.f);
    }
    #pragma unroll
    for (int i = 0; i < 2; ++i) {
        int idx = tid + i * 512;
        if (idx < 810) cwl[idx] = cw[(idx % 15) * 54 + idx / 15];
    }
    __syncthreads();

    // fill xpad interior (600 float4: ch 0-2 = xd, 3-5 = xres) -- TWO passes (R10 bug:
    // single pass with 512 threads left elements 512..599 unwritten)
    const float* src0 = xd + (size_t)b * 1200;
    const float* src1 = xres + (size_t)b * 1200;
    #pragma unroll
    for (int i = 0; i < 2; ++i) {
        int j = tid + i * 512;
        if (j < 600) {
            float4 v = (j < 300) ? ((const float4*)src0)[j] : ((const float4*)src1)[j - 300];
            int c = j / 100, rr = (j % 100) * 4, y = rr / 20, x = rr % 20;
            float* dst = xpad + c * 484 + (y + 1) * 22 + (x + 1);
            dst[0] = v.x; dst[1] = v.y; dst[2] = v.z; dst[3] = v.w;
        }
    }
    __syncthreads();

    // ---- conv phase: 500 active threads, one row-quad x 3 channels each ----
    const bool act = (tid < 500);
    const int u = act ? tid : 499;
    const int g = u / 100, s = u % 100;
    const int r = s / 5, xc = s % 5;
    const int xq = 4 * xc;
    const int o0 = 3 * g;

    float a[3][4];
    #pragma unroll
    for (int cc = 0; cc < 3; ++cc) {
        float bo = cb[o0 + cc];
        #pragma unroll
        for (int sl = 0; sl < 4; ++sl) a[cc][sl] = bo;
    }

    #pragma unroll
    for (int ci = 0; ci < 6; ++ci) {
        float P[3][6];
        #pragma unroll
        for (int kk = 0; kk < 3; ++kk) {
            const float* rp = xpad + ci * 484 + (r + kk) * 22 + xq;
            #pragma unroll
            for (int t = 0; t < 6; ++t) P[kk][t] = rp[t];
        }
        #pragma unroll
        for (int ky = 0; ky < 3; ++ky) {
            const int tb = (ci * 9 + ky * 3) * 15 + o0;
            #pragma unroll
            for (int cc = 0; cc < 3; ++cc) {
                float w0 = cwl[tb + cc], w1v = cwl[tb + 15 + cc], w2v = cwl[tb + 30 + cc];
                #pragma unroll
                for (int sl = 0; sl < 4; ++sl)
                    a[cc][sl] = fmaf(P[ky][sl], w0,
                                fmaf(P[ky][sl + 1], w1v,
                                fmaf(P[ky][sl + 2], w2v, a[cc][sl])));
            }
        }
    }
    if (act) {
        const int q4 = 4 * (5 * r + xc);
        #pragma unroll
        for (int cc = 0; cc < 3; ++cc)
            *(float4*)(wl + (o0 + cc) * 404 + q4) =
                make_float4(a[cc][0], a[cc][1], a[cc][2], a[cc][3]);
    }
    __syncthreads();

    // ---- Gram phase: pos = tid < 400; consecutive-address scalar reads ----
    float g15[15];
    #pragma unroll
    for (int v = 0; v < 15; ++v) g15[v] = 0.f;
    if (tid < 400) {
        const int pos = tid;
        #pragma unroll
        for (int cc = 0; cc < 3; ++cc) {
            float ch[5];
            #pragma unroll
            for (int i = 0; i < 5; ++i) ch[i] = wl[(3 * i + cc) * 404 + pos];
            int p = 0;
            #pragma unroll
            for (int i = 0; i < 5; ++i)
                #pragma unroll
                for (int j = i; j < 5; ++j, ++p)
                    g15[p] = fmaf(ch[i], ch[j], g15[p]);
        }
    }
    #pragma unroll
    for (int m = 32; m; m >>= 1) {
        #pragma unroll
        for (int v = 0; v < 15; ++v) g15[v] += __shfl_xor(g15[v], m, 64);
    }
    if (lane == 0) {
        #pragma unroll
        for (int v = 0; v < 15; ++v) gred[wv][v] = g15[v];
    }
    __syncthreads();

    // ---- A-matrix (Gram-space modified GS, per-thread redundant) + combine + store ----
    float Gm[15];
    #pragma unroll
    for (int v = 0; v < 15; ++v)
        Gm[v] = ((gred[0][v] + gred[1][v]) + (gred[2][v] + gred[3][v])) +
                ((gred[4][v] + gred[5][v]) + (gred[6][v] + gred[7][v]));

    float A[5][5];
    #pragma unroll
    for (int i = 0; i < 5; ++i)
        #pragma unroll
        for (int j = 0; j < 5; ++j) A[i][j] = (i == j) ? 1.f : 0.f;
    #pragma unroll
    for (int j = 0; j < 4; ++j) {
        float v[5];
        #pragma unroll
        for (int rr = 0; rr < 5; ++rr) {
            float s0 = 0.f;
            #pragma unroll
            for (int k = 0; k < 5; ++k)
                if (k <= j) s0 = fmaf(A[j][k], GF(k, rr), s0);
            v[rr] = s0;
        }
        float dj = 0.f;
        #pragma unroll
        for (int k = 0; k < 5; ++k)
            if (k <= j) dj = fmaf(A[j][k], v[k], dj);
        float rd = 1.0f / dj;
        #pragma unroll
        for (int i = j + 1; i < 5; ++i) {
            float cij = 0.f;
            #pragma unroll
            for (int k = 0; k < 5; ++k)
                if (k <= i) cij = fmaf(A[i][k], v[k], cij);
            cij *= rd;
            #pragma unroll
            for (int k = 0; k < 5; ++k)
                if (k <= j) A[i][k] = fmaf(-cij, A[j][k], A[i][k]);
        }
    }

    if (tid < 400) {
        const int pos = tid;
        float* ob = out + (size_t)b * 6000;
        #pragma unroll
        for (int cc = 0; cc < 3; ++cc) {
            float wq[5];
            #pragma unroll
            for (int k = 0; k < 5; ++k) wq[k] = wl[(3 * k + cc) * 404 + pos];
            #pragma unroll
            for (int d = 4; d >= 0; --d) {
                float uo = wq[d];
                #pragma unroll
                for (int k = 0; k < d; ++k) uo = fmaf(A[d][k], wq[k], uo);
                ob[(3 * d + cc) * 400 + pos] = uo;
            }
        }
    }
}

extern "C" void kernel_launch(void* const* d_in, const int* in_sizes, int n_in,
                              void* d_out, int out_size, void* d_ws, size_t ws_size,
                              hipStream_t stream) {
    const float* x_restored  = (const float*)d_in[0];
    const float* x_distorted = (const float*)d_in[1];
    const float* w1          = (const float*)d_in[2];
    const float* w2          = (const float*)d_in[3];
    const float* b2          = (const float*)d_in[4];
    const float* conv_w      = (const float*)d_in[5];
    const float* conv_b      = (const float*)d_in[6];
    float* out = (float*)d_out;

    float* xd = (float*)d_ws;                                         // 39.3 MB
    unsigned short* hb  = (unsigned short*)(xd + (size_t)NB * 1200);  // 2 MB
    unsigned short* w2b = hb + (size_t)NB * 128;                      // 0.3 MB

    mlp1_kernel<<<(NB * 128) / 256, 256, 0, stream>>>(x_distorted, w1, hb);
    castw2_kernel<<<(1200 * 128) / 256, 256, 0, stream>>>(w2, w2b);
    mlp2_mfma<<<(128 * 25) / 4, 256, 0, stream>>>(hb, w2b, b2, xd);
    conv_gs_kernel<<<NB, 512, 0, stream>>>(xd, x_restored, conv_w, conv_b, out);
}

// Round 13
// 125.096 us; speedup vs baseline: 12.2507x; 2.0109x over previous
//
#include <hip/hip_runtime.h>

// x_restored: (8192, 3, 20, 20) f32
// x_distorted: (8192, 5) f32
// w1: (128, 5), w2: (1200, 128), b2: (1200,)
// conv_w: (15, 6, 3, 3), conv_b: (15,)
// out: (8192, 5, 3, 20, 20) f32

#define NB 8192

typedef __attribute__((ext_vector_type(8))) short short8;
typedef __attribute__((ext_vector_type(4))) float floatx4;
typedef unsigned short u16;

__device__ inline u16 f2bf(float f) {
    unsigned int u = __float_as_uint(f);
    unsigned int r = (u + 0x7FFFu + ((u >> 16) & 1u)) >> 16;
    return (u16)r;
}

// ---------------- Kernel A: h = relu(x_distorted @ w1.T) -> bf16, (B,128) ----------------
__global__ __launch_bounds__(256) void mlp1_kernel(const float* __restrict__ xdist,
                                                   const float* __restrict__ w1,
                                                   u16* __restrict__ hb) {
    int gid = blockIdx.x * 256 + threadIdx.x;
    int b = gid >> 7, j = gid & 127;
    const float* xr = xdist + b * 5;
    const float* wr = w1 + j * 5;
    float s = xr[0] * wr[0];
    s = fmaf(xr[1], wr[1], s);
    s = fmaf(xr[2], wr[2], s);
    s = fmaf(xr[3], wr[3], s);
    s = fmaf(xr[4], wr[4], s);
    hb[gid] = f2bf(fmaxf(s, 0.0f));
}

// ---------------- cast w2 -> bf16 ----------------
__global__ __launch_bounds__(256) void castw2_kernel(const float* __restrict__ w2,
                                                     u16* __restrict__ w2b) {
    int i = blockIdx.x * 256 + threadIdx.x;   // 1200*128 = 153600 exactly
    w2b[i] = f2bf(w2[i]);
}

// ---------------- Kernel B: xd = h @ w2.T + b2 via bf16 MFMA; OUTPUT IN BF16 ----------------
__global__ __launch_bounds__(256) void mlp2_mfma(const u16* __restrict__ hb,
                                                 const u16* __restrict__ w2b,
                                                 const float* __restrict__ b2,
                                                 u16* __restrict__ xdb) {
    const int tid = threadIdx.x;
    const int lane = tid & 63, wv = tid >> 6;
    const int tile = blockIdx.x * 4 + wv;          // 0..3199
    const int mt = tile / 25, nt = tile - mt * 25;
    const int rsel = lane & 15, kg = lane >> 4;

    short8 a[4][4], bfr[3][4];
    #pragma unroll
    for (int mi = 0; mi < 4; ++mi) {
        const u16* ap = hb + (size_t)(mt * 64 + mi * 16 + rsel) * 128 + kg * 8;
        #pragma unroll
        for (int ks = 0; ks < 4; ++ks) a[mi][ks] = *(const short8*)(ap + ks * 32);
    }
    #pragma unroll
    for (int ni = 0; ni < 3; ++ni) {
        const u16* bp = w2b + (size_t)(nt * 48 + ni * 16 + rsel) * 128 + kg * 8;
        #pragma unroll
        for (int ks = 0; ks < 4; ++ks) bfr[ni][ks] = *(const short8*)(bp + ks * 32);
    }
    floatx4 acc[4][3];
    #pragma unroll
    for (int mi = 0; mi < 4; ++mi)
        #pragma unroll
        for (int ni = 0; ni < 3; ++ni)
            acc[mi][ni] = (floatx4){0.f, 0.f, 0.f, 0.f};

    #pragma unroll
    for (int ks = 0; ks < 4; ++ks)
        #pragma unroll
        for (int mi = 0; mi < 4; ++mi)
            #pragma unroll
            for (int ni = 0; ni < 3; ++ni)
                acc[mi][ni] = __builtin_amdgcn_mfma_f32_16x16x32_bf16(
                    a[mi][ks], bfr[ni][ks], acc[mi][ni], 0, 0, 0);

    #pragma unroll
    for (int ni = 0; ni < 3; ++ni) {
        float bias = b2[nt * 48 + ni * 16 + rsel];
        #pragma unroll
        for (int mi = 0; mi < 4; ++mi) {
            #pragma unroll
            for (int r = 0; r < 4; ++r) {
                int m = mt * 64 + mi * 16 + kg * 4 + r;
                xdb[(size_t)m * 1200 + nt * 48 + ni * 16 + rsel] = f2bf(acc[mi][ni][r] + bias);
            }
        }
    }
}

#define GIDX(i, j) ((i) * 5 - (i) * ((i) - 1) / 2 + ((j) - (i)))
#define GF(i, j) Gm[((i) <= (j)) ? GIDX(i, j) : GIDX(j, i)]

#define XS2 23            // padded row stride (ushorts)
#define XPL 506           // plane stride = 22*23
#define WLS 401           // wl row stride (odd -> conflict-free writes/reads)

// ---------------- Kernel C: conv(6->15) via MFMA + Gram-space GS, 256 thr / sample --------
// Conv as implicit GEMM: C[px][oc] = sum_k X[px][k] W[oc][k], K=54 pad 64, M=25x16 tiles,
// N=16 (15 oc + 1 pad col). A-frags gathered as bf16 ds_read_u16 from bf16 xpad with
// per-lane precomputed k->offset table; B-frags (weights) built once per thread. Same
// fragment pattern as the verified mlp2_mfma. R12 bug fixed here: xpad is 3040 u16 =
// 1520 DWORDS; the zero loop only covered 760 -> uninitialized pad border read as bf16
// NaN. Now 6 passes x 256 = 1536 >= 1520.
__global__ __launch_bounds__(256) void conv_gs_kernel(const u16* __restrict__ xdb,
                                                      const float* __restrict__ xres,
                                                      const float* __restrict__ cw,
                                                      const float* __restrict__ cb,
                                                      float* __restrict__ out) {
    const int b = blockIdx.x;
    const int tid = threadIdx.x;  // 0..255
    const int lane = tid & 63, wv = tid >> 6;
    const int rsel = lane & 15, kg = lane >> 4;
    __shared__ __align__(16) u16 xpad[3040];     // 6 padded 22x23 bf16 planes (3036 used)
    __shared__ __align__(16) float wl[15 * WLS]; // conv output [oc][px], stride 401
    __shared__ float gred[4][16];
    __shared__ float Ash[12];

    // ---- per-thread setup (no LDS dependencies; overlaps zero/fill) ----
    // B-fragments: lane holds W[oc=rsel][k = s*32 + kg*8 + j] (0 for oc=15 or k>=54)
    short8 bf0, bf1;
    #pragma unroll
    for (int j = 0; j < 8; ++j) {
        int k0 = kg * 8 + j;
        int k1 = 32 + kg * 8 + j;
        float v0 = (rsel < 15 && k0 < 54) ? cw[rsel * 54 + k0] : 0.f;
        float v1 = (rsel < 15 && k1 < 54) ? cw[rsel * 54 + k1] : 0.f;
        bf0[j] = (short)f2bf(v0);
        bf1[j] = (short)f2bf(v1);
    }
    const float bias = cb[rsel < 15 ? rsel : 14];
    // A-gather offset table: k -> ci*XPL + dy*XS2 + dx (0 if k>=54; B=0 there anyway)
    int offA[16];
    #pragma unroll
    for (int q = 0; q < 16; ++q) {
        int k = (q >> 3) * 32 + kg * 8 + (q & 7);
        int ci = k / 9, tap = k - ci * 9, dy = tap / 3, dx = tap - dy * 3;
        offA[q] = (k < 54) ? (ci * XPL + dy * XS2 + dx) : 0;
    }

    // ---- zero xpad: 3040 u16 = 1520 dwords (R12 bug: only zeroed 760) ----
    unsigned int* xz = (unsigned int*)xpad;
    #pragma unroll
    for (int i2 = 0; i2 < 6; ++i2) {
        int i = tid + i2 * 256;
        if (i < 1520) xz[i] = 0u;
    }
    __syncthreads();

    // ---- fill interior: ch 0-2 from xdb (already bf16, plain copy), 3-5 from xres (cvt)
    const u16* s0 = xdb + (size_t)b * 1200;
    const float* s1 = xres + (size_t)b * 1200;
    #pragma unroll
    for (int i2 = 0; i2 < 5; ++i2) {
        int i = tid + i2 * 256;
        if (i < 1200) {
            int c = i / 400, p = i - c * 400, y = p / 20, x = p - y * 20;
            xpad[c * XPL + (y + 1) * XS2 + (x + 1)] = s0[i];
        }
    }
    #pragma unroll
    for (int i2 = 0; i2 < 5; ++i2) {
        int i = tid + i2 * 256;
        if (i < 1200) {
            int c = i / 400 + 3, p = i % 400, y = p / 20, x = p - (p / 20) * 20;
            xpad[c * XPL + (y + 1) * XS2 + (x + 1)] = f2bf(s1[i]);
        }
    }
    __syncthreads();

    // ---- conv via MFMA: wave wv handles tiles t = wv, wv+4, ... < 25 ----
    for (int t = wv; t < 25; t += 4) {
        const int px = t * 16 + rsel;            // A-row owned by this lane
        const int y = px / 20;
        const int pb = y * XS2 + (px - y * 20);  // window top-left in padded plane
        short8 a0, a1;
        #pragma unroll
        for (int j = 0; j < 8; ++j) a0[j] = (short)xpad[pb + offA[j]];
        #pragma unroll
        for (int j = 0; j < 8; ++j) a1[j] = (short)xpad[pb + offA[8 + j]];
        floatx4 acc = (floatx4){0.f, 0.f, 0.f, 0.f};
        acc = __builtin_amdgcn_mfma_f32_16x16x32_bf16(a0, bf0, acc, 0, 0, 0);
        acc = __builtin_amdgcn_mfma_f32_16x16x32_bf16(a1, bf1, acc, 0, 0, 0);
        // C layout: col = lane&15 = oc, row = kg*4 + reg = px-in-tile
        if (rsel < 15) {
            const int wb = rsel * WLS + t * 16 + kg * 4;
            wl[wb + 0] = acc[0] + bias;
            wl[wb + 1] = acc[1] + bias;
            wl[wb + 2] = acc[2] + bias;
            wl[wb + 3] = acc[3] + bias;
        }
    }
    __syncthreads();

    // ---- Gram phase: tid<200, pos = tid, tid+200; consecutive-address scalar reads ----
    float g15[15];
    #pragma unroll
    for (int v = 0; v < 15; ++v) g15[v] = 0.f;
    if (tid < 200) {
        #pragma unroll
        for (int pp = 0; pp < 2; ++pp) {
            const int pos = tid + pp * 200;
            #pragma unroll
            for (int cc = 0; cc < 3; ++cc) {
                float ch[5];
                #pragma unroll
                for (int i = 0; i < 5; ++i) ch[i] = wl[(3 * i + cc) * WLS + pos];
                int p = 0;
                #pragma unroll
                for (int i = 0; i < 5; ++i)
                    #pragma unroll
                    for (int j = i; j < 5; ++j, ++p)
                        g15[p] = fmaf(ch[i], ch[j], g15[p]);
            }
        }
    }
    #pragma unroll
    for (int m = 32; m; m >>= 1) {
        #pragma unroll
        for (int v = 0; v < 15; ++v) g15[v] += __shfl_xor(g15[v], m, 64);
    }
    if (lane == 0) {
        #pragma unroll
        for (int v = 0; v < 15; ++v) gred[wv][v] = g15[v];
    }
    __syncthreads();

    // ---- A-matrix: wave 0 only (Gram-space modified GS), broadcast via LDS ----
    if (tid < 64) {
        float Gm[15];
        #pragma unroll
        for (int v = 0; v < 15; ++v)
            Gm[v] = (gred[0][v] + gred[1][v]) + (gred[2][v] + gred[3][v]);

        float A[5][5];
        #pragma unroll
        for (int i = 0; i < 5; ++i)
            #pragma unroll
            for (int j = 0; j < 5; ++j) A[i][j] = (i == j) ? 1.f : 0.f;
        #pragma unroll
        for (int j = 0; j < 4; ++j) {
            float v[5];
            #pragma unroll
            for (int rr = 0; rr < 5; ++rr) {
                float s0a = 0.f;
                #pragma unroll
                for (int k = 0; k < 5; ++k)
                    if (k <= j) s0a = fmaf(A[j][k], GF(k, rr), s0a);
                v[rr] = s0a;
            }
            float dj = 0.f;
            #pragma unroll
            for (int k = 0; k < 5; ++k)
                if (k <= j) dj = fmaf(A[j][k], v[k], dj);
            float rd = 1.0f / dj;
            #pragma unroll
            for (int i = j + 1; i < 5; ++i) {
                float cij = 0.f;
                #pragma unroll
                for (int k = 0; k < 5; ++k)
                    if (k <= i) cij = fmaf(A[i][k], v[k], cij);
                cij *= rd;
                #pragma unroll
                for (int k = 0; k < 5; ++k)
                    if (k <= j) A[i][k] = fmaf(-cij, A[j][k], A[i][k]);
            }
        }
        if (tid == 0) {
            Ash[0] = A[1][0];
            Ash[1] = A[2][0]; Ash[2] = A[2][1];
            Ash[3] = A[3][0]; Ash[4] = A[3][1]; Ash[5] = A[3][2];
            Ash[6] = A[4][0]; Ash[7] = A[4][1]; Ash[8] = A[4][2]; Ash[9] = A[4][3];
        }
    }
    __syncthreads();

    // ---- combine + store: tid<200, 2 positions, coalesced scalar stores ----
    if (tid < 200) {
        float a10[10];
        #pragma unroll
        for (int q = 0; q < 10; ++q) a10[q] = Ash[q];
        float* ob = out + (size_t)b * 6000;
        #pragma unroll
        for (int pp = 0; pp < 2; ++pp) {
            const int pos = tid + pp * 200;
            #pragma unroll
            for (int cc = 0; cc < 3; ++cc) {
                float w0 = wl[(0 + cc) * WLS + pos];
                float w1 = wl[(3 + cc) * WLS + pos];
                float w2v = wl[(6 + cc) * WLS + pos];
                float w3 = wl[(9 + cc) * WLS + pos];
                float w4 = wl[(12 + cc) * WLS + pos];
                float u4 = fmaf(a10[9], w3, fmaf(a10[8], w2v, fmaf(a10[7], w1, fmaf(a10[6], w0, w4))));
                float u3 = fmaf(a10[5], w2v, fmaf(a10[4], w1, fmaf(a10[3], w0, w3)));
                float u2 = fmaf(a10[2], w1, fmaf(a10[1], w0, w2v));
                float u1 = fmaf(a10[0], w0, w1);
                ob[(0 + cc) * 400 + pos] = w0;
                ob[(3 + cc) * 400 + pos] = u1;
                ob[(6 + cc) * 400 + pos] = u2;
                ob[(9 + cc) * 400 + pos] = u3;
                ob[(12 + cc) * 400 + pos] = u4;
            }
        }
    }
}

extern "C" void kernel_launch(void* const* d_in, const int* in_sizes, int n_in,
                              void* d_out, int out_size, void* d_ws, size_t ws_size,
                              hipStream_t stream) {
    const float* x_restored  = (const float*)d_in[0];
    const float* x_distorted = (const float*)d_in[1];
    const float* w1          = (const float*)d_in[2];
    const float* w2          = (const float*)d_in[3];
    const float* b2          = (const float*)d_in[4];
    const float* conv_w      = (const float*)d_in[5];
    const float* conv_b      = (const float*)d_in[6];
    float* out = (float*)d_out;

    u16* xdb = (u16*)d_ws;                           // 8192*1200 bf16 = 19.7 MB
    u16* hb  = xdb + (size_t)NB * 1200;              // 8192*128 bf16 = 2 MB
    u16* w2b = hb + (size_t)NB * 128;                // 1200*128 bf16 = 0.3 MB

    mlp1_kernel<<<(NB * 128) / 256, 256, 0, stream>>>(x_distorted, w1, hb);
    castw2_kernel<<<(1200 * 128) / 256, 256, 0, stream>>>(w2, w2b);
    mlp2_mfma<<<(128 * 25) / 4, 256, 0, stream>>>(hb, w2b, b2, xdb);
    conv_gs_kernel<<<NB, 256, 0, stream>>>(xdb, x_restored, conv_w, conv_b, out);
}

// Round 14
// 107.801 us; speedup vs baseline: 14.2162x; 1.1604x over previous
//
#include <hip/hip_runtime.h>

// x_restored: (8192, 3, 20, 20) f32
// x_distorted: (8192, 5) f32
// w1: (128, 5), w2: (1200, 128), b2: (1200,)
// conv_w: (15, 6, 3, 3), conv_b: (15,)
// out: (8192, 5, 3, 20, 20) f32

#define NB 8192

typedef __attribute__((ext_vector_type(8))) short short8;
typedef __attribute__((ext_vector_type(4))) float floatx4;
typedef unsigned short u16;

__device__ inline u16 f2bf(float f) {
    unsigned int u = __float_as_uint(f);
    unsigned int r = (u + 0x7FFFu + ((u >> 16) & 1u)) >> 16;
    return (u16)r;
}
__device__ inline float bf2f(u16 u) {
    return __uint_as_float(((unsigned int)u) << 16);
}

// ---------------- Kernel A: h = relu(x_distorted @ w1.T) -> bf16, (B,128) ----------------
__global__ __launch_bounds__(256) void mlp1_kernel(const float* __restrict__ xdist,
                                                   const float* __restrict__ w1,
                                                   u16* __restrict__ hb) {
    int gid = blockIdx.x * 256 + threadIdx.x;
    int b = gid >> 7, j = gid & 127;
    const float* xr = xdist + b * 5;
    const float* wr = w1 + j * 5;
    float s = xr[0] * wr[0];
    s = fmaf(xr[1], wr[1], s);
    s = fmaf(xr[2], wr[2], s);
    s = fmaf(xr[3], wr[3], s);
    s = fmaf(xr[4], wr[4], s);
    hb[gid] = f2bf(fmaxf(s, 0.0f));
}

// ---------------- cast w2 -> bf16 ----------------
__global__ __launch_bounds__(256) void castw2_kernel(const float* __restrict__ w2,
                                                     u16* __restrict__ w2b) {
    int i = blockIdx.x * 256 + threadIdx.x;   // 1200*128 = 153600 exactly
    w2b[i] = f2bf(w2[i]);
}

// ---------------- Kernel B: xd = h @ w2.T + b2 via bf16 MFMA; OUTPUT IN BF16 ----------------
__global__ __launch_bounds__(256) void mlp2_mfma(const u16* __restrict__ hb,
                                                 const u16* __restrict__ w2b,
                                                 const float* __restrict__ b2,
                                                 u16* __restrict__ xdb) {
    const int tid = threadIdx.x;
    const int lane = tid & 63, wv = tid >> 6;
    const int tile = blockIdx.x * 4 + wv;          // 0..3199
    const int mt = tile / 25, nt = tile - mt * 25;
    const int rsel = lane & 15, kg = lane >> 4;

    short8 a[4][4], bfr[3][4];
    #pragma unroll
    for (int mi = 0; mi < 4; ++mi) {
        const u16* ap = hb + (size_t)(mt * 64 + mi * 16 + rsel) * 128 + kg * 8;
        #pragma unroll
        for (int ks = 0; ks < 4; ++ks) a[mi][ks] = *(const short8*)(ap + ks * 32);
    }
    #pragma unroll
    for (int ni = 0; ni < 3; ++ni) {
        const u16* bp = w2b + (size_t)(nt * 48 + ni * 16 + rsel) * 128 + kg * 8;
        #pragma unroll
        for (int ks = 0; ks < 4; ++ks) bfr[ni][ks] = *(const short8*)(bp + ks * 32);
    }
    floatx4 acc[4][3];
    #pragma unroll
    for (int mi = 0; mi < 4; ++mi)
        #pragma unroll
        for (int ni = 0; ni < 3; ++ni)
            acc[mi][ni] = (floatx4){0.f, 0.f, 0.f, 0.f};

    #pragma unroll
    for (int ks = 0; ks < 4; ++ks)
        #pragma unroll
        for (int mi = 0; mi < 4; ++mi)
            #pragma unroll
            for (int ni = 0; ni < 3; ++ni)
                acc[mi][ni] = __builtin_amdgcn_mfma_f32_16x16x32_bf16(
                    a[mi][ks], bfr[ni][ks], acc[mi][ni], 0, 0, 0);

    #pragma unroll
    for (int ni = 0; ni < 3; ++ni) {
        float bias = b2[nt * 48 + ni * 16 + rsel];
        #pragma unroll
        for (int mi = 0; mi < 4; ++mi) {
            #pragma unroll
            for (int r = 0; r < 4; ++r) {
                int m = mt * 64 + mi * 16 + kg * 4 + r;
                xdb[(size_t)m * 1200 + nt * 48 + ni * 16 + rsel] = f2bf(acc[mi][ni][r] + bias);
            }
        }
    }
}

#define GIDX(i, j) ((i) * 5 - (i) * ((i) - 1) / 2 + ((j) - (i)))
#define GF(i, j) Gm[((i) <= (j)) ? GIDX(i, j) : GIDX(j, i)]

#define XS2 23            // xpad row stride (ushorts)
#define XPL 506           // xpad plane stride = 22*23
#define WLS 400           // wl row stride (u16 units; even -> b64-aligned quad writes)

// ---------------- Kernel C: conv(6->15) via MFMA + Gram-space GS, 256 thr / sample --------
// R13 + three LDS-pipe cuts:
//  (1) Gram reduction: DPP-only shuffles (masks 1-8, VALU pipe) + 16-group LDS tree --
//      removes the 30 ds_bpermute ops (masks 16/32) and their lgkm waits.
//  (2) wl stored as bf16 [15][400]: conv writes 1x ds_write_b64 per tile (2x
//      v_cvt_pk_bf16_f32), Gram/combine read u16+lshl. LDS 30.7 -> 19.3 KB (8 blk/CU).
//  (3) everything else identical to the verified R13.
__global__ __launch_bounds__(256) void conv_gs_kernel(const u16* __restrict__ xdb,
                                                      const float* __restrict__ xres,
                                                      const float* __restrict__ cw,
                                                      const float* __restrict__ cb,
                                                      float* __restrict__ out) {
    const int b = blockIdx.x;
    const int tid = threadIdx.x;  // 0..255
    const int lane = tid & 63, wv = tid >> 6;
    const int rsel = lane & 15, kg = lane >> 4;
    __shared__ __align__(16) u16 xpad[3040];       // 6 padded 22x23 bf16 planes
    __shared__ __align__(16) u16 wl16[15 * WLS];   // conv output bf16 [oc][px]
    __shared__ float gsc[16 * 17];                 // 16-group Gram partials (pad 17)
    __shared__ float gfin[16];
    __shared__ float Ash[12];

    // ---- per-thread setup ----
    short8 bf0, bf1;
    #pragma unroll
    for (int j = 0; j < 8; ++j) {
        int k0 = kg * 8 + j;
        int k1 = 32 + kg * 8 + j;
        float v0 = (rsel < 15 && k0 < 54) ? cw[rsel * 54 + k0] : 0.f;
        float v1 = (rsel < 15 && k1 < 54) ? cw[rsel * 54 + k1] : 0.f;
        bf0[j] = (short)f2bf(v0);
        bf1[j] = (short)f2bf(v1);
    }
    const float bias = cb[rsel < 15 ? rsel : 14];
    int offA[16];
    #pragma unroll
    for (int q = 0; q < 16; ++q) {
        int k = (q >> 3) * 32 + kg * 8 + (q & 7);
        int ci = k / 9, tap = k - ci * 9, dy = tap / 3, dx = tap - dy * 3;
        offA[q] = (k < 54) ? (ci * XPL + dy * XS2 + dx) : 0;
    }

    // ---- zero xpad: 3040 u16 = 1520 dwords ----
    unsigned int* xz = (unsigned int*)xpad;
    #pragma unroll
    for (int i2 = 0; i2 < 6; ++i2) {
        int i = tid + i2 * 256;
        if (i < 1520) xz[i] = 0u;
    }
    __syncthreads();

    // ---- fill interior: ch 0-2 from xdb (bf16 copy), 3-5 from xres (cvt) ----
    const u16* s0 = xdb + (size_t)b * 1200;
    const float* s1 = xres + (size_t)b * 1200;
    #pragma unroll
    for (int i2 = 0; i2 < 5; ++i2) {
        int i = tid + i2 * 256;
        if (i < 1200) {
            int c = i / 400, p = i - c * 400, y = p / 20, x = p - y * 20;
            xpad[c * XPL + (y + 1) * XS2 + (x + 1)] = s0[i];
        }
    }
    #pragma unroll
    for (int i2 = 0; i2 < 5; ++i2) {
        int i = tid + i2 * 256;
        if (i < 1200) {
            int c = i / 400 + 3, p = i % 400, y = p / 20, x = p - (p / 20) * 20;
            xpad[c * XPL + (y + 1) * XS2 + (x + 1)] = f2bf(s1[i]);
        }
    }
    __syncthreads();

    // ---- conv via MFMA: wave wv handles tiles t = wv, wv+4, ... < 25 ----
    for (int t = wv; t < 25; t += 4) {
        const int px = t * 16 + rsel;
        const int y = px / 20;
        const int pb = y * XS2 + (px - y * 20);
        short8 a0, a1;
        #pragma unroll
        for (int j = 0; j < 8; ++j) a0[j] = (short)xpad[pb + offA[j]];
        #pragma unroll
        for (int j = 0; j < 8; ++j) a1[j] = (short)xpad[pb + offA[8 + j]];
        floatx4 acc = (floatx4){0.f, 0.f, 0.f, 0.f};
        acc = __builtin_amdgcn_mfma_f32_16x16x32_bf16(a0, bf0, acc, 0, 0, 0);
        acc = __builtin_amdgcn_mfma_f32_16x16x32_bf16(a1, bf1, acc, 0, 0, 0);
        // C layout: col = rsel = oc, row = kg*4 + reg = px-in-tile
        if (rsel < 15) {
            float v0 = acc[0] + bias, v1 = acc[1] + bias;
            float v2 = acc[2] + bias, v3 = acc[3] + bias;
            unsigned int lo, hi;
            asm volatile("v_cvt_pk_bf16_f32 %0, %1, %2" : "=v"(lo) : "v"(v0), "v"(v1));
            asm volatile("v_cvt_pk_bf16_f32 %0, %1, %2" : "=v"(hi) : "v"(v2), "v"(v3));
            *(uint2*)(wl16 + rsel * WLS + t * 16 + kg * 4) = make_uint2(lo, hi);
        }
    }
    __syncthreads();

    // ---- Gram partials: tid<200, pos = tid, tid+200; consecutive-address u16 reads ----
    float g15[15];
    #pragma unroll
    for (int v = 0; v < 15; ++v) g15[v] = 0.f;
    if (tid < 200) {
        #pragma unroll
        for (int pp = 0; pp < 2; ++pp) {
            const int pos = tid + pp * 200;
            #pragma unroll
            for (int cc = 0; cc < 3; ++cc) {
                float ch[5];
                #pragma unroll
                for (int i = 0; i < 5; ++i) ch[i] = bf2f(wl16[(3 * i + cc) * WLS + pos]);
                int p = 0;
                #pragma unroll
                for (int i = 0; i < 5; ++i)
                    #pragma unroll
                    for (int j = i; j < 5; ++j, ++p)
                        g15[p] = fmaf(ch[i], ch[j], g15[p]);
            }
        }
    }
    // DPP-only reduction within 16-lane groups (masks 1,2,4,8 stay in-row -> VALU pipe)
    #pragma unroll
    for (int m = 8; m; m >>= 1) {
        #pragma unroll
        for (int v = 0; v < 15; ++v) g15[v] += __shfl_xor(g15[v], m, 64);
    }
    if ((tid & 15) == 0) {
        const int grp = tid >> 4;   // 0..15
        #pragma unroll
        for (int v = 0; v < 15; ++v) gsc[grp * 17 + v] = g15[v];
    }
    __syncthreads();
    // final tree: threads 0..14 (wave 0) sum the 16 group partials
    if (tid < 15) {
        float s = 0.f;
        #pragma unroll
        for (int g = 0; g < 16; ++g) s += gsc[g * 17 + tid];
        gfin[tid] = s;
    }
    // ---- A-matrix: wave 0 only (same-wave ds ordering: no barrier needed after gfin) ----
    if (tid < 64) {
        float Gm[15];
        #pragma unroll
        for (int v = 0; v < 15; ++v) Gm[v] = gfin[v];

        float A[5][5];
        #pragma unroll
        for (int i = 0; i < 5; ++i)
            #pragma unroll
            for (int j = 0; j < 5; ++j) A[i][j] = (i == j) ? 1.f : 0.f;
        #pragma unroll
        for (int j = 0; j < 4; ++j) {
            float v[5];
            #pragma unroll
            for (int rr = 0; rr < 5; ++rr) {
                float s0a = 0.f;
                #pragma unroll
                for (int k = 0; k < 5; ++k)
                    if (k <= j) s0a = fmaf(A[j][k], GF(k, rr), s0a);
                v[rr] = s0a;
            }
            float dj = 0.f;
            #pragma unroll
            for (int k = 0; k < 5; ++k)
                if (k <= j) dj = fmaf(A[j][k], v[k], dj);
            float rd = 1.0f / dj;
            #pragma unroll
            for (int i = j + 1; i < 5; ++i) {
                float cij = 0.f;
                #pragma unroll
                for (int k = 0; k < 5; ++k)
                    if (k <= i) cij = fmaf(A[i][k], v[k], cij);
                cij *= rd;
                #pragma unroll
                for (int k = 0; k < 5; ++k)
                    if (k <= j) A[i][k] = fmaf(-cij, A[j][k], A[i][k]);
            }
        }
        if (tid == 0) {
            Ash[0] = A[1][0];
            Ash[1] = A[2][0]; Ash[2] = A[2][1];
            Ash[3] = A[3][0]; Ash[4] = A[3][1]; Ash[5] = A[3][2];
            Ash[6] = A[4][0]; Ash[7] = A[4][1]; Ash[8] = A[4][2]; Ash[9] = A[4][3];
        }
    }
    __syncthreads();

    // ---- combine + store: tid<200, 2 positions, coalesced scalar stores ----
    if (tid < 200) {
        float a10[10];
        #pragma unroll
        for (int q = 0; q < 10; ++q) a10[q] = Ash[q];
        float* ob = out + (size_t)b * 6000;
        #pragma unroll
        for (int pp = 0; pp < 2; ++pp) {
            const int pos = tid + pp * 200;
            #pragma unroll
            for (int cc = 0; cc < 3; ++cc) {
                float w0 = bf2f(wl16[(0 + cc) * WLS + pos]);
                float w1 = bf2f(wl16[(3 + cc) * WLS + pos]);
                float w2v = bf2f(wl16[(6 + cc) * WLS + pos]);
                float w3 = bf2f(wl16[(9 + cc) * WLS + pos]);
                float w4 = bf2f(wl16[(12 + cc) * WLS + pos]);
                float u4 = fmaf(a10[9], w3, fmaf(a10[8], w2v, fmaf(a10[7], w1, fmaf(a10[6], w0, w4))));
                float u3 = fmaf(a10[5], w2v, fmaf(a10[4], w1, fmaf(a10[3], w0, w3)));
                float u2 = fmaf(a10[2], w1, fmaf(a10[1], w0, w2v));
                float u1 = fmaf(a10[0], w0, w1);
                ob[(0 + cc) * 400 + pos] = w0;
                ob[(3 + cc) * 400 + pos] = u1;
                ob[(6 + cc) * 400 + pos] = u2;
                ob[(9 + cc) * 400 + pos] = u3;
                ob[(12 + cc) * 400 + pos] = u4;
            }
        }
    }
}

extern "C" void kernel_launch(void* const* d_in, const int* in_sizes, int n_in,
                              void* d_out, int out_size, void* d_ws, size_t ws_size,
                              hipStream_t stream) {
    const float* x_restored  = (const float*)d_in[0];
    const float* x_distorted = (const float*)d_in[1];
    const float* w1          = (const float*)d_in[2];
    const float* w2          = (const float*)d_in[3];
    const float* b2          = (const float*)d_in[4];
    const float* conv_w      = (const float*)d_in[5];
    const float* conv_b      = (const float*)d_in[6];
    float* out = (float*)d_out;

    u16* xdb = (u16*)d_ws;                           // 8192*1200 bf16 = 19.7 MB
    u16* hb  = xdb + (size_t)NB * 1200;              // 8192*128 bf16 = 2 MB
    u16* w2b = hb + (size_t)NB * 128;                // 1200*128 bf16 = 0.3 MB

    mlp1_kernel<<<(NB * 128) / 256, 256, 0, stream>>>(x_distorted, w1, hb);
    castw2_kernel<<<(1200 * 128) / 256, 256, 0, stream>>>(w2, w2b);
    mlp2_mfma<<<(128 * 25) / 4, 256, 0, stream>>>(hb, w2b, b2, xdb);
    conv_gs_kernel<<<NB, 256, 0, stream>>>(xdb, x_restored, conv_w, conv_b, out);
}